// Round 13
// baseline (61.454 us; speedup 1.0000x reference)
//
#include <hip/hip_runtime.h>
#include <hip/hip_fp16.h>

// NCC (local normalized cross-correlation) loss, win=9^3, SAME zero padding.
// Volume: (B=2, C=1, D=160, H=192, W=160) fp32. Output: scalar fp32 loss.
//
// v11: y-boxsum + cc moved to the (idle) MFMA pipe.
//  - y-boxsum is a banded matmul: S[y][x] = sum_k W[y][k] R[k][x], W 16x24
//    0/1 band (k-y in [0,8]) -> one mfma_f32_16x16x32_bf16 per (q, x-half):
//    10 MFMAs/step replace P3 (384 LDS-cyc) + P4 (140) + the Sq buffer.
//  - P2 writes bf16 x-sums in the ds_read_b64_tr_b16 tile layout:
//    elem(k,n) = n + 16*(k&3) + 64*(k>>3) + 256*((k>>2)&1); rows 24..31
//    zeroed once (K=32 pad). tr read: per-lane addr 2*(l&15)+128*(l>>4),
//    second read +512B; lgkmcnt(0)+sched_barrier(0) before MFMA (rule #18).
//  - waves 0/1 own x-half 0/1 (cc needs all 5 q in one lane; D gives
//    4 y-rows x 1 x per lane per half). Waves 2/3 idle in that phase only.
//  - barriers 4 -> 2 per step; sub-slice global loads issue before the MFMA
//    block (T14: ~200cyc L2 latency hides under tr+MFMA+cc).
//  - LDS 22.5 KB (Zq fp16 stride 48 + RqT bf16 10x544); lgkm-only barriers;
//    ZC=8, 2400 blocks, XCD swizzle; deterministic two-stage reduction.

#define NX 160
#define NY 192
#define NZ 160
#define NB 2
#define SLICE (NX * NY)            // 30720
#define VOL   (SLICE * NZ)         // 4915200
#define TOTAL (VOL * NB)           // 9830400

#define TX 32
#define TY 16
#define ZC 8
#define GXT (NX / TX)              // 5
#define GYT (NY / TY)              // 12
#define GZT (NZ / ZC)              // 20
#define NBLK (GXT * GYT * GZT * NB) // 2400

#define HR 24                      // y halo rows
#define ZQS 48                     // Zq row stride (halfs), 96B, 16B-aligned
#define ZQQ (HR * ZQS + 8)         // 1160
#define RGN 544                    // RqT region elems (512 data + 32 pad)
#define INV729 (1.0f / 729.0f)

typedef short bf16x8 __attribute__((ext_vector_type(8)));
typedef float f32x4 __attribute__((ext_vector_type(4)));

__device__ __forceinline__ void lds_barrier() {
    // LDS-visibility barrier WITHOUT vmcnt drain: prefetched global loads
    // stay in flight (hipcc's __syncthreads would emit s_waitcnt vmcnt(0)).
    asm volatile("s_waitcnt lgkmcnt(0)" ::: "memory");
    __builtin_amdgcn_s_barrier();
}

__device__ __forceinline__ unsigned cvt_pk_bf16(float lo, float hi) {
    unsigned r;
    asm("v_cvt_pk_bf16_f32 %0, %1, %2" : "=v"(r) : "v"(lo), "v"(hi));
    return r;
}

__device__ __forceinline__ uint2 tr_rd(unsigned a) {
    uint2 d;
    asm volatile("ds_read_b64_tr_b16 %0, %1" : "=v"(d) : "v"(a));
    return d;
}

__device__ __forceinline__ float4 f4add(float4 a, float4 b) {
    return make_float4(a.x + b.x, a.y + b.y, a.z + b.z, a.w + b.w);
}
__device__ __forceinline__ float4 f4sub(float4 a, float4 b) {
    return make_float4(a.x - b.x, a.y - b.y, a.z - b.z, a.w - b.w);
}
__device__ __forceinline__ float4 f4mul(float4 a, float4 b) {
    return make_float4(a.x * b.x, a.y * b.y, a.z * b.z, a.w * b.w);
}

union U8 { uint4 u; __half2 h[4]; };
__device__ __forceinline__ U8 ld8(const __half* p) {
    U8 r; r.u = *(const uint4*)p; return r;
}

__global__ __launch_bounds__(256) void ncc_main(
    const float* __restrict__ J_pred,   // predict
    const float* __restrict__ I_targ,   // target
    float* __restrict__ partial)
{
    const int tid = threadIdx.x;

    // XCD-chunked swizzle: 8 XCDs x 300 consecutive logical blocks (bijective).
    const int lin = blockIdx.x;
    const int s   = (lin & 7) * (NBLK / 8) + (lin >> 3);
    const int bx  = s % GXT;
    const int r1  = s / GXT;
    const int by  = r1 % GYT;
    const int r2  = r1 / GYT;
    const int zc  = r2 % GZT;
    const int b   = r2 / GZT;

    const int x0 = bx * TX;
    const int y0 = by * TY;
    const int z0 = zc * ZC;

    __shared__ __align__(16) __half Zq[5 * ZQQ];    // 11600 B (fp16 z-sums)
    __shared__ __align__(16) short  RqT[10 * RGN];  // 10880 B (bf16 x-sums, tr tiles)
    __shared__ float redbuf[4];

    // ---- one-time: zero K-pad rows 24..31 of every region ----
    if (tid < 160) {
        const int r = tid >> 4, slot = tid & 15;
        const int e = (slot < 8) ? (192 + slot * 8) : (448 + (slot - 8) * 8);
        *(uint4*)&RqT[r * RGN + e] = make_uint4(0, 0, 0, 0);
    }

    // ---- float4 column ownership: 240 tasks = 24 rows x 10 groups ----
    const bool is_col = (tid < 240);
    const int  crow = tid / 10;
    const int  cxg  = tid - crow * 10;
    const int  gy = y0 - 4 + crow;
    const int  gx = x0 - 4 + cxg * 4;
    const bool vxy = is_col && ((unsigned)gy < (unsigned)NY) && (gx >= 0) && (gx <= NX - 4);
    const size_t cbase = (size_t)b * VOL + (vxy ? (size_t)(gy * NX + gx) : 0);
    const float* const baseI = I_targ + cbase;
    const float* const baseJ = J_pred + cbase;

    // ---- MFMA constants: banded W fragment + tr-read base address ----
    const int lane = tid & 63;
    bf16x8 wfrag;
    {
        const int m = lane & 15, kb = (lane >> 4) * 8;
#pragma unroll
        for (int j = 0; j < 8; ++j) {
            const int k = kb + j;
            wfrag[j] = (k >= m && k <= m + 8) ? (short)0x3F80 : (short)0;
        }
    }
    const unsigned rqbase = (unsigned)(size_t)&RqT[0];
    const unsigned trlane = rqbase + 2u * (unsigned)(lane & 15) + 128u * (unsigned)(lane >> 4);

    // ---- running z-box-sums (fp32, exact sliding) ----
    const float4 f40 = make_float4(0.f, 0.f, 0.f, 0.f);
    float4 rS0 = f40, rS1 = f40, rS2 = f40, rS3 = f40, rS4 = f40;

    // warmup: add slices z0-5 .. z0+3 (OOB z -> zeros); P0 of step s always
    // subtracts z0+s-5, which at s=0 removes the z0-5 added here.
#pragma unroll 1
    for (int ss = 0; ss < 9; ++ss) {
        const int z = z0 - 5 + ss;
        float4 aI = f40, aJ = f40;
        if (vxy && (unsigned)z < (unsigned)NZ) {
            aI = *(const float4*)(baseI + (size_t)z * SLICE);
            aJ = *(const float4*)(baseJ + (size_t)z * SLICE);
        }
        rS0 = f4add(rS0, aI);
        rS1 = f4add(rS1, aJ);
        rS2 = f4add(rS2, f4mul(aI, aI));
        rS3 = f4add(rS3, f4mul(aJ, aJ));
        rS4 = f4add(rS4, f4mul(aI, aJ));
    }

    // pending add-slice for step 0 (z0+4 always < NZ)
    float4 nIa = f40, nJa = f40;
    if (vxy) {
        nIa = *(const float4*)(baseI + (size_t)(z0 + 4) * SLICE);
        nJa = *(const float4*)(baseJ + (size_t)(z0 + 4) * SLICE);
    }

    float acc = 0.f;

    // ---- phase lambdas ----
    auto do_P1 = [&]() {   // stage z-sums as fp16
        if (is_col) {
            const int o = crow * ZQS + cxg * 4;
            union { uint2 u; __half2 h[2]; } pk;
            pk.h[0] = __float22half2_rn(make_float2(rS0.x, rS0.y));
            pk.h[1] = __float22half2_rn(make_float2(rS0.z, rS0.w));
            *(uint2*)&Zq[0 * ZQQ + o] = pk.u;
            pk.h[0] = __float22half2_rn(make_float2(rS1.x, rS1.y));
            pk.h[1] = __float22half2_rn(make_float2(rS1.z, rS1.w));
            *(uint2*)&Zq[1 * ZQQ + o] = pk.u;
            pk.h[0] = __float22half2_rn(make_float2(rS2.x, rS2.y));
            pk.h[1] = __float22half2_rn(make_float2(rS2.z, rS2.w));
            *(uint2*)&Zq[2 * ZQQ + o] = pk.u;
            pk.h[0] = __float22half2_rn(make_float2(rS3.x, rS3.y));
            pk.h[1] = __float22half2_rn(make_float2(rS3.z, rS3.w));
            *(uint2*)&Zq[3 * ZQQ + o] = pk.u;
            pk.h[0] = __float22half2_rn(make_float2(rS4.x, rS4.y));
            pk.h[1] = __float22half2_rn(make_float2(rS4.z, rS4.w));
            *(uint2*)&Zq[4 * ZQQ + o] = pk.u;
        }
    };

    auto do_P2 = [&]() {   // x-boxsum: fp16 in, f32 slide, bf16 tr-tile out
        if (tid < 240) {
            const int q   = tid / 48;
            const int rem = tid - q * 48;
            const int row = rem >> 1;
            const int h   = rem & 1;
            const __half* src = &Zq[q * ZQQ + row * ZQS + h * 16];
            float c[24];
#pragma unroll
            for (int g = 0; g < 3; ++g) {
                U8 v = ld8(src + g * 8);
#pragma unroll
                for (int j = 0; j < 4; ++j) {
                    const float2 f = __half22float2(v.h[j]);
                    c[g * 8 + j * 2 + 0] = f.x;
                    c[g * 8 + j * 2 + 1] = f.y;
                }
            }
            float sx = c[0] + c[1] + c[2] + c[3] + c[4]
                     + c[5] + c[6] + c[7] + c[8];
            float o[16];
            o[0] = sx;
#pragma unroll
            for (int i = 1; i < 16; ++i) { sx += c[i + 8] - c[i - 1]; o[i] = sx; }
            unsigned u[8];
#pragma unroll
            for (int i = 0; i < 8; ++i) u[i] = cvt_pk_bf16(o[2 * i], o[2 * i + 1]);
            const int e = 16 * (row & 3) + 64 * (row >> 3) + 256 * ((row >> 2) & 1);
            short* dst = &RqT[(q * 2 + h) * RGN + e];
            *(uint4*)(dst + 0) = make_uint4(u[0], u[1], u[2], u[3]);
            *(uint4*)(dst + 8) = make_uint4(u[4], u[5], u[6], u[7]);
        }
    };

    auto do_mfmacc = [&]() {   // y-boxsum via MFMA + cc, waves 0/1 only
        if (tid < 128) {
            const int h = tid >> 6;                     // x-half
            const unsigned abase = trlane + (unsigned)h * 1088u;
            const f32x4 z4 = {0.f, 0.f, 0.f, 0.f};
            f32x4 D[5];
#pragma unroll
            for (int q = 0; q < 5; ++q) {
                const unsigned a = abase + (unsigned)q * 2176u;
                uint2 b0 = tr_rd(a);
                uint2 b1 = tr_rd(a + 512u);
                asm volatile("s_waitcnt lgkmcnt(0)" ::: "memory");
                __builtin_amdgcn_sched_barrier(0);
                union { uint2 u[2]; bf16x8 v; } bb;
                bb.u[0] = b0; bb.u[1] = b1;
                D[q] = __builtin_amdgcn_mfma_f32_16x16x32_bf16(wfrag, bb.v, z4, 0, 0, 0);
            }
#pragma unroll
            for (int r = 0; r < 4; ++r) {
                const float S0 = D[0][r], S1 = D[1][r], S2 = D[2][r],
                            S3 = D[3][r], S4 = D[4][r];
                const float cross = S4 - S0 * S1 * INV729;
                const float Iv    = S2 - S0 * S0 * INV729;
                const float Jv    = S3 - S1 * S1 * INV729;
                acc += (cross * cross) / (Iv * Jv + 1e-5f);
            }
        }
    };

    // ---- prologue: step 0 staged through its x-boxsum ----
    {
        // P0(0): add pending z0+4; sub z0-5 (<0 at zc==0 -> zeros)
        float4 sI = f40, sJ = f40;
        const int zs = z0 - 5;
        if (vxy && zs >= 0) {
            sI = *(const float4*)(baseI + (size_t)zs * SLICE);
            sJ = *(const float4*)(baseJ + (size_t)zs * SLICE);
        }
        rS0 = f4add(rS0, f4sub(nIa, sI));
        rS1 = f4add(rS1, f4sub(nJa, sJ));
        rS2 = f4add(rS2, f4sub(f4mul(nIa, nIa), f4mul(sI, sI)));
        rS3 = f4add(rS3, f4sub(f4mul(nJa, nJa), f4mul(sJ, sJ)));
        rS4 = f4add(rS4, f4sub(f4mul(nIa, nJa), f4mul(sI, sJ)));
        nIa = f40; nJa = f40;
        if (vxy) {   // prefetch add-slice for step 1 (z0+5 < NZ always)
            nIa = *(const float4*)(baseI + (size_t)(z0 + 5) * SLICE);
            nJa = *(const float4*)(baseJ + (size_t)(z0 + 5) * SLICE);
        }
        do_P1();
        lds_barrier();   // barA
        do_P2();
        lds_barrier();   // barB
    }

    // ---- 2-barrier body: stage step t+1, consume step t ----
#pragma unroll 1
    for (int t = 0; t < ZC - 1; ++t) {
        const int ss = t + 1;
        // P0a: issue sub loads early (L2 latency hides under tr+MFMA+cc)
        float4 sI = f40, sJ = f40;
        const int zs = z0 + ss - 5;
        if (vxy && zs >= 0) {
            sI = *(const float4*)(baseI + (size_t)zs * SLICE);
            sJ = *(const float4*)(baseJ + (size_t)zs * SLICE);
        }

        do_mfmacc();     // consume step t (reads RqT(t), regs only after)

        // P0b: z-window update for step ss + prefetch add for ss+1
        rS0 = f4add(rS0, f4sub(nIa, sI));
        rS1 = f4add(rS1, f4sub(nJa, sJ));
        rS2 = f4add(rS2, f4sub(f4mul(nIa, nIa), f4mul(sI, sI)));
        rS3 = f4add(rS3, f4sub(f4mul(nJa, nJa), f4mul(sJ, sJ)));
        rS4 = f4add(rS4, f4sub(f4mul(nIa, nJa), f4mul(sI, sJ)));
        nIa = f40; nJa = f40;
        if (ss < ZC - 1 && vxy) {
            const int za = z0 + 5 + ss;
            if (za < NZ) {
                nIa = *(const float4*)(baseI + (size_t)za * SLICE);
                nJa = *(const float4*)(baseJ + (size_t)za * SLICE);
            }
        }

        do_P1();         // stage Zq(ss)  [Zq readers of step t done before barB(t-1)]
        lds_barrier();   // barA: Zq(ss) ready; RqT(t) reads complete
        do_P2();         // RqT(ss)
        lds_barrier();   // barB: RqT(ss) ready
    }

    do_mfmacc();         // consume final step ZC-1

    // ---- block reduction (deterministic within block) ----
#pragma unroll
    for (int off = 32; off > 0; off >>= 1) acc += __shfl_down(acc, off);
    __syncthreads();
    if ((tid & 63) == 0) redbuf[tid >> 6] = acc;
    __syncthreads();
    if (tid == 0) partial[s] = redbuf[0] + redbuf[1] + redbuf[2] + redbuf[3];
}

__global__ __launch_bounds__(256) void ncc_final(
    const float* __restrict__ partial, float* __restrict__ out)
{
    __shared__ float sm[256];
    const int tid = threadIdx.x;
    float v = 0.f;
    for (int i = tid; i < NBLK; i += 256) v += partial[i];
    sm[tid] = v;
    __syncthreads();
#pragma unroll
    for (int w = 128; w > 0; w >>= 1) {
        if (tid < w) sm[tid] += sm[tid + w];
        __syncthreads();
    }
    if (tid == 0) out[0] = 1.0f - sm[0] * (1.0f / (float)TOTAL);
}

extern "C" void kernel_launch(void* const* d_in, const int* in_sizes, int n_in,
                              void* d_out, int out_size, void* d_ws, size_t ws_size,
                              hipStream_t stream)
{
    const float* predict = (const float*)d_in[0];  // J
    const float* target  = (const float*)d_in[1];  // I
    float* partial = (float*)d_ws;                 // 2400 floats (9.6 KB)

    ncc_main<<<dim3(NBLK), 256, 0, stream>>>(predict, target, partial);
    ncc_final<<<1, 256, 0, stream>>>(partial, (float*)d_out);
}

// Round 14
// 61.448 us; speedup vs baseline: 1.0001x; 1.0001x over previous
//
#include <hip/hip_runtime.h>
#include <hip/hip_fp16.h>

// NCC (local normalized cross-correlation) loss, win=9^3, SAME zero padding.
// Volume: (B=2, C=1, D=160, H=192, W=160) fp32. Output: scalar fp32 loss.
//
// v11: y-boxsum + cc moved to the (idle) MFMA pipe.
//  - y-boxsum is a banded matmul: S[y][x] = sum_k W[y][k] R[k][x], W 16x24
//    0/1 band (k-y in [0,8]) -> one mfma_f32_16x16x32_bf16 per (q, x-half):
//    10 MFMAs/step replace P3 (384 LDS-cyc) + P4 (140) + the Sq buffer.
//  - P2 writes bf16 x-sums in the ds_read_b64_tr_b16 tile layout:
//    elem(k,n) = n + 16*(k&3) + 64*(k>>3) + 256*((k>>2)&1); rows 24..31
//    zeroed once (K=32 pad). tr read: per-lane addr 2*(l&15)+128*(l>>4),
//    second read +512B; lgkmcnt(0)+sched_barrier(0) before MFMA (rule #18).
//  - waves 0/1 own x-half 0/1 (cc needs all 5 q in one lane; D gives
//    4 y-rows x 1 x per lane per half). Waves 2/3 idle in that phase only.
//  - barriers 4 -> 2 per step; sub-slice global loads issue before the MFMA
//    block (T14: ~200cyc L2 latency hides under tr+MFMA+cc).
//  - LDS 22.5 KB (Zq fp16 stride 48 + RqT bf16 10x544); lgkm-only barriers;
//    ZC=8, 2400 blocks, XCD swizzle; deterministic two-stage reduction.

#define NX 160
#define NY 192
#define NZ 160
#define NB 2
#define SLICE (NX * NY)            // 30720
#define VOL   (SLICE * NZ)         // 4915200
#define TOTAL (VOL * NB)           // 9830400

#define TX 32
#define TY 16
#define ZC 8
#define GXT (NX / TX)              // 5
#define GYT (NY / TY)              // 12
#define GZT (NZ / ZC)              // 20
#define NBLK (GXT * GYT * GZT * NB) // 2400

#define HR 24                      // y halo rows
#define ZQS 48                     // Zq row stride (halfs), 96B, 16B-aligned
#define ZQQ (HR * ZQS + 8)         // 1160
#define RGN 544                    // RqT region elems (512 data + 32 pad)
#define INV729 (1.0f / 729.0f)

typedef short bf16x8 __attribute__((ext_vector_type(8)));
typedef float f32x4 __attribute__((ext_vector_type(4)));

__device__ __forceinline__ void lds_barrier() {
    // LDS-visibility barrier WITHOUT vmcnt drain: prefetched global loads
    // stay in flight (hipcc's __syncthreads would emit s_waitcnt vmcnt(0)).
    asm volatile("s_waitcnt lgkmcnt(0)" ::: "memory");
    __builtin_amdgcn_s_barrier();
}

__device__ __forceinline__ unsigned cvt_pk_bf16(float lo, float hi) {
    unsigned r;
    asm("v_cvt_pk_bf16_f32 %0, %1, %2" : "=v"(r) : "v"(lo), "v"(hi));
    return r;
}

__device__ __forceinline__ uint2 tr_rd(unsigned a) {
    uint2 d;
    asm volatile("ds_read_b64_tr_b16 %0, %1" : "=v"(d) : "v"(a));
    return d;
}

__device__ __forceinline__ float4 f4add(float4 a, float4 b) {
    return make_float4(a.x + b.x, a.y + b.y, a.z + b.z, a.w + b.w);
}
__device__ __forceinline__ float4 f4sub(float4 a, float4 b) {
    return make_float4(a.x - b.x, a.y - b.y, a.z - b.z, a.w - b.w);
}
__device__ __forceinline__ float4 f4mul(float4 a, float4 b) {
    return make_float4(a.x * b.x, a.y * b.y, a.z * b.z, a.w * b.w);
}

union U8 { uint4 u; __half2 h[4]; };
__device__ __forceinline__ U8 ld8(const __half* p) {
    U8 r; r.u = *(const uint4*)p; return r;
}

__global__ __launch_bounds__(256) void ncc_main(
    const float* __restrict__ J_pred,   // predict
    const float* __restrict__ I_targ,   // target
    float* __restrict__ partial)
{
    const int tid = threadIdx.x;

    // XCD-chunked swizzle: 8 XCDs x 300 consecutive logical blocks (bijective).
    const int lin = blockIdx.x;
    const int s   = (lin & 7) * (NBLK / 8) + (lin >> 3);
    const int bx  = s % GXT;
    const int r1  = s / GXT;
    const int by  = r1 % GYT;
    const int r2  = r1 / GYT;
    const int zc  = r2 % GZT;
    const int b   = r2 / GZT;

    const int x0 = bx * TX;
    const int y0 = by * TY;
    const int z0 = zc * ZC;

    __shared__ __align__(16) __half Zq[5 * ZQQ];    // 11600 B (fp16 z-sums)
    __shared__ __align__(16) short  RqT[10 * RGN];  // 10880 B (bf16 x-sums, tr tiles)
    __shared__ float redbuf[4];

    // ---- one-time: zero K-pad rows 24..31 of every region ----
    if (tid < 160) {
        const int r = tid >> 4, slot = tid & 15;
        const int e = (slot < 8) ? (192 + slot * 8) : (448 + (slot - 8) * 8);
        *(uint4*)&RqT[r * RGN + e] = make_uint4(0, 0, 0, 0);
    }

    // ---- float4 column ownership: 240 tasks = 24 rows x 10 groups ----
    const bool is_col = (tid < 240);
    const int  crow = tid / 10;
    const int  cxg  = tid - crow * 10;
    const int  gy = y0 - 4 + crow;
    const int  gx = x0 - 4 + cxg * 4;
    const bool vxy = is_col && ((unsigned)gy < (unsigned)NY) && (gx >= 0) && (gx <= NX - 4);
    const size_t cbase = (size_t)b * VOL + (vxy ? (size_t)(gy * NX + gx) : 0);
    const float* const baseI = I_targ + cbase;
    const float* const baseJ = J_pred + cbase;

    // ---- MFMA constants: banded W fragment + tr-read base address ----
    const int lane = tid & 63;
    bf16x8 wfrag;
    {
        const int m = lane & 15, kb = (lane >> 4) * 8;
#pragma unroll
        for (int j = 0; j < 8; ++j) {
            const int k = kb + j;
            wfrag[j] = (k >= m && k <= m + 8) ? (short)0x3F80 : (short)0;
        }
    }
    const unsigned rqbase = (unsigned)(size_t)&RqT[0];
    const unsigned trlane = rqbase + 2u * (unsigned)(lane & 15) + 128u * (unsigned)(lane >> 4);

    // ---- running z-box-sums (fp32, exact sliding) ----
    const float4 f40 = make_float4(0.f, 0.f, 0.f, 0.f);
    float4 rS0 = f40, rS1 = f40, rS2 = f40, rS3 = f40, rS4 = f40;

    // warmup: add slices z0-5 .. z0+3 (OOB z -> zeros); P0 of step s always
    // subtracts z0+s-5, which at s=0 removes the z0-5 added here.
#pragma unroll 1
    for (int ss = 0; ss < 9; ++ss) {
        const int z = z0 - 5 + ss;
        float4 aI = f40, aJ = f40;
        if (vxy && (unsigned)z < (unsigned)NZ) {
            aI = *(const float4*)(baseI + (size_t)z * SLICE);
            aJ = *(const float4*)(baseJ + (size_t)z * SLICE);
        }
        rS0 = f4add(rS0, aI);
        rS1 = f4add(rS1, aJ);
        rS2 = f4add(rS2, f4mul(aI, aI));
        rS3 = f4add(rS3, f4mul(aJ, aJ));
        rS4 = f4add(rS4, f4mul(aI, aJ));
    }

    // pending add-slice for step 0 (z0+4 always < NZ)
    float4 nIa = f40, nJa = f40;
    if (vxy) {
        nIa = *(const float4*)(baseI + (size_t)(z0 + 4) * SLICE);
        nJa = *(const float4*)(baseJ + (size_t)(z0 + 4) * SLICE);
    }

    float acc = 0.f;

    // ---- phase lambdas ----
    auto do_P1 = [&]() {   // stage z-sums as fp16
        if (is_col) {
            const int o = crow * ZQS + cxg * 4;
            union { uint2 u; __half2 h[2]; } pk;
            pk.h[0] = __float22half2_rn(make_float2(rS0.x, rS0.y));
            pk.h[1] = __float22half2_rn(make_float2(rS0.z, rS0.w));
            *(uint2*)&Zq[0 * ZQQ + o] = pk.u;
            pk.h[0] = __float22half2_rn(make_float2(rS1.x, rS1.y));
            pk.h[1] = __float22half2_rn(make_float2(rS1.z, rS1.w));
            *(uint2*)&Zq[1 * ZQQ + o] = pk.u;
            pk.h[0] = __float22half2_rn(make_float2(rS2.x, rS2.y));
            pk.h[1] = __float22half2_rn(make_float2(rS2.z, rS2.w));
            *(uint2*)&Zq[2 * ZQQ + o] = pk.u;
            pk.h[0] = __float22half2_rn(make_float2(rS3.x, rS3.y));
            pk.h[1] = __float22half2_rn(make_float2(rS3.z, rS3.w));
            *(uint2*)&Zq[3 * ZQQ + o] = pk.u;
            pk.h[0] = __float22half2_rn(make_float2(rS4.x, rS4.y));
            pk.h[1] = __float22half2_rn(make_float2(rS4.z, rS4.w));
            *(uint2*)&Zq[4 * ZQQ + o] = pk.u;
        }
    };

    auto do_P2 = [&]() {   // x-boxsum: fp16 in, f32 slide, bf16 tr-tile out
        if (tid < 240) {
            const int q   = tid / 48;
            const int rem = tid - q * 48;
            const int row = rem >> 1;
            const int h   = rem & 1;
            const __half* src = &Zq[q * ZQQ + row * ZQS + h * 16];
            float c[24];
#pragma unroll
            for (int g = 0; g < 3; ++g) {
                U8 v = ld8(src + g * 8);
#pragma unroll
                for (int j = 0; j < 4; ++j) {
                    const float2 f = __half22float2(v.h[j]);
                    c[g * 8 + j * 2 + 0] = f.x;
                    c[g * 8 + j * 2 + 1] = f.y;
                }
            }
            float sx = c[0] + c[1] + c[2] + c[3] + c[4]
                     + c[5] + c[6] + c[7] + c[8];
            float o[16];
            o[0] = sx;
#pragma unroll
            for (int i = 1; i < 16; ++i) { sx += c[i + 8] - c[i - 1]; o[i] = sx; }
            unsigned u[8];
#pragma unroll
            for (int i = 0; i < 8; ++i) u[i] = cvt_pk_bf16(o[2 * i], o[2 * i + 1]);
            const int e = 16 * (row & 3) + 64 * (row >> 3) + 256 * ((row >> 2) & 1);
            short* dst = &RqT[(q * 2 + h) * RGN + e];
            *(uint4*)(dst + 0) = make_uint4(u[0], u[1], u[2], u[3]);
            *(uint4*)(dst + 8) = make_uint4(u[4], u[5], u[6], u[7]);
        }
    };

    auto do_mfmacc = [&]() {   // y-boxsum via MFMA + cc, waves 0/1 only
        if (tid < 128) {
            const int h = tid >> 6;                     // x-half
            const unsigned abase = trlane + (unsigned)h * 1088u;
            const f32x4 z4 = {0.f, 0.f, 0.f, 0.f};
            f32x4 D[5];
#pragma unroll
            for (int q = 0; q < 5; ++q) {
                const unsigned a = abase + (unsigned)q * 2176u;
                uint2 b0 = tr_rd(a);
                uint2 b1 = tr_rd(a + 512u);
                asm volatile("s_waitcnt lgkmcnt(0)" ::: "memory");
                __builtin_amdgcn_sched_barrier(0);
                union { uint2 u[2]; bf16x8 v; } bb;
                bb.u[0] = b0; bb.u[1] = b1;
                D[q] = __builtin_amdgcn_mfma_f32_16x16x32_bf16(wfrag, bb.v, z4, 0, 0, 0);
            }
#pragma unroll
            for (int r = 0; r < 4; ++r) {
                const float S0 = D[0][r], S1 = D[1][r], S2 = D[2][r],
                            S3 = D[3][r], S4 = D[4][r];
                const float cross = S4 - S0 * S1 * INV729;
                const float Iv    = S2 - S0 * S0 * INV729;
                const float Jv    = S3 - S1 * S1 * INV729;
                acc += (cross * cross) / (Iv * Jv + 1e-5f);
            }
        }
    };

    // ---- prologue: step 0 staged through its x-boxsum ----
    {
        // P0(0): add pending z0+4; sub z0-5 (<0 at zc==0 -> zeros)
        float4 sI = f40, sJ = f40;
        const int zs = z0 - 5;
        if (vxy && zs >= 0) {
            sI = *(const float4*)(baseI + (size_t)zs * SLICE);
            sJ = *(const float4*)(baseJ + (size_t)zs * SLICE);
        }
        rS0 = f4add(rS0, f4sub(nIa, sI));
        rS1 = f4add(rS1, f4sub(nJa, sJ));
        rS2 = f4add(rS2, f4sub(f4mul(nIa, nIa), f4mul(sI, sI)));
        rS3 = f4add(rS3, f4sub(f4mul(nJa, nJa), f4mul(sJ, sJ)));
        rS4 = f4add(rS4, f4sub(f4mul(nIa, nJa), f4mul(sI, sJ)));
        nIa = f40; nJa = f40;
        if (vxy) {   // prefetch add-slice for step 1 (z0+5 < NZ always)
            nIa = *(const float4*)(baseI + (size_t)(z0 + 5) * SLICE);
            nJa = *(const float4*)(baseJ + (size_t)(z0 + 5) * SLICE);
        }
        do_P1();
        lds_barrier();   // barA
        do_P2();
        lds_barrier();   // barB
    }

    // ---- 2-barrier body: stage step t+1, consume step t ----
#pragma unroll 1
    for (int t = 0; t < ZC - 1; ++t) {
        const int ss = t + 1;
        // P0a: issue sub loads early (L2 latency hides under tr+MFMA+cc)
        float4 sI = f40, sJ = f40;
        const int zs = z0 + ss - 5;
        if (vxy && zs >= 0) {
            sI = *(const float4*)(baseI + (size_t)zs * SLICE);
            sJ = *(const float4*)(baseJ + (size_t)zs * SLICE);
        }

        do_mfmacc();     // consume step t (reads RqT(t), regs only after)

        // P0b: z-window update for step ss + prefetch add for ss+1
        rS0 = f4add(rS0, f4sub(nIa, sI));
        rS1 = f4add(rS1, f4sub(nJa, sJ));
        rS2 = f4add(rS2, f4sub(f4mul(nIa, nIa), f4mul(sI, sI)));
        rS3 = f4add(rS3, f4sub(f4mul(nJa, nJa), f4mul(sJ, sJ)));
        rS4 = f4add(rS4, f4sub(f4mul(nIa, nJa), f4mul(sI, sJ)));
        nIa = f40; nJa = f40;
        if (ss < ZC - 1 && vxy) {
            const int za = z0 + 5 + ss;
            if (za < NZ) {
                nIa = *(const float4*)(baseI + (size_t)za * SLICE);
                nJa = *(const float4*)(baseJ + (size_t)za * SLICE);
            }
        }

        do_P1();         // stage Zq(ss)  [Zq readers of step t done before barB(t-1)]
        lds_barrier();   // barA: Zq(ss) ready; RqT(t) reads complete
        do_P2();         // RqT(ss)
        lds_barrier();   // barB: RqT(ss) ready
    }

    do_mfmacc();         // consume final step ZC-1

    // ---- block reduction (deterministic within block) ----
#pragma unroll
    for (int off = 32; off > 0; off >>= 1) acc += __shfl_down(acc, off);
    __syncthreads();
    if ((tid & 63) == 0) redbuf[tid >> 6] = acc;
    __syncthreads();
    if (tid == 0) partial[s] = redbuf[0] + redbuf[1] + redbuf[2] + redbuf[3];
}

__global__ __launch_bounds__(256) void ncc_final(
    const float* __restrict__ partial, float* __restrict__ out)
{
    __shared__ float sm[256];
    const int tid = threadIdx.x;
    float v = 0.f;
    for (int i = tid; i < NBLK; i += 256) v += partial[i];
    sm[tid] = v;
    __syncthreads();
#pragma unroll
    for (int w = 128; w > 0; w >>= 1) {
        if (tid < w) sm[tid] += sm[tid + w];
        __syncthreads();
    }
    if (tid == 0) out[0] = 1.0f - sm[0] * (1.0f / (float)TOTAL);
}

extern "C" void kernel_launch(void* const* d_in, const int* in_sizes, int n_in,
                              void* d_out, int out_size, void* d_ws, size_t ws_size,
                              hipStream_t stream)
{
    const float* predict = (const float*)d_in[0];  // J
    const float* target  = (const float*)d_in[1];  // I
    float* partial = (float*)d_ws;                 // 2400 floats (9.6 KB)

    ncc_main<<<dim3(NBLK), 256, 0, stream>>>(predict, target, partial);
    ncc_final<<<1, 256, 0, stream>>>(partial, (float*)d_out);
}

// Round 15
// 59.991 us; speedup vs baseline: 1.0244x; 1.0243x over previous
//
#include <hip/hip_runtime.h>
#include <hip/hip_fp16.h>

// NCC (local normalized cross-correlation) loss, win=9^3, SAME zero padding.
// Volume: (B=2, C=1, D=160, H=192, W=160) fp32. Output: scalar fp32 loss.
//
// v12: v8 (best, 60.6us) + occupancy levers only.
//  - Cross-round evidence: occupancy tracks grid size (480blk->26%,
//    2400->41%, 4320->64%), never the LDS cap. Waves idle ~82% of each
//    step; more resident blocks is the only proven filler.
//  - ZC=5 (GZT=32): 3840 blocks = 15/CU of work (was 9.4).
//  - Zq stride 56->40 halfs: LDS 23.55 -> 19.4 KB -> 8 blocks/CU cap
//    (VGPR 44 allows 8 waves/SIMD).
//  - Everything else identical to v8: fp16 LDS staging, fp32 z-slide/cc,
//    4 lgkm-only barriers (global prefetch survives), Sq aliases Zq,
//    float4 column loads + full-step prefetch, 240/80-task phase split,
//    bijective XCD swizzle, deterministic two-stage reduction.

#define NX 160
#define NY 192
#define NZ 160
#define NB 2
#define SLICE (NX * NY)            // 30720
#define VOL   (SLICE * NZ)         // 4915200
#define TOTAL (VOL * NB)           // 9830400

#define TX 32
#define TY 16
#define ZC 5
#define GXT (NX / TX)              // 5
#define GYT (NY / TY)              // 12
#define GZT (NZ / ZC)              // 32
#define NBLK (GXT * GYT * GZT * NB) // 3840

#define HY 24                      // y halo rows
#define ZRS 40                     // Zq row stride (fp16): 80B, 16B-aligned
#define ZQQ (HY * ZRS + 8)         // 968 fp16 per quantity plane
#define RRS 40                     // Rq row stride (fp16): 80B
#define RQQ (HY * RRS + 8)         // 968
#define SRS 40                     // Sq row stride (fp16): 80B (alias in Zq)
#define SQQ (TY * SRS + 8)         // 648
#define INV729 (1.0f / 729.0f)

__device__ __forceinline__ void lds_barrier() {
    // LDS-visibility barrier WITHOUT vmcnt drain: prefetched global loads
    // stay in flight (hipcc's __syncthreads would emit s_waitcnt vmcnt(0)).
    asm volatile("s_waitcnt lgkmcnt(0)" ::: "memory");
    __builtin_amdgcn_s_barrier();
}

__device__ __forceinline__ float4 f4add(float4 a, float4 b) {
    return make_float4(a.x + b.x, a.y + b.y, a.z + b.z, a.w + b.w);
}
__device__ __forceinline__ float4 f4sub(float4 a, float4 b) {
    return make_float4(a.x - b.x, a.y - b.y, a.z - b.z, a.w - b.w);
}
__device__ __forceinline__ float4 f4mul(float4 a, float4 b) {
    return make_float4(a.x * b.x, a.y * b.y, a.z * b.z, a.w * b.w);
}

union U8 { uint4 u; __half2 h[4]; };   // 8 fp16 = one b128

__device__ __forceinline__ U8 ld8(const __half* p) {
    U8 r; r.u = *(const uint4*)p; return r;
}
__device__ __forceinline__ void st8(__half* p, const U8& v) {
    *(uint4*)p = v.u;
}

__global__ __launch_bounds__(256) void ncc_main(
    const float* __restrict__ J_pred,   // predict
    const float* __restrict__ I_targ,   // target
    float* __restrict__ partial)
{
    const int tid = threadIdx.x;

    // XCD-chunked swizzle: 8 XCDs x 480 consecutive logical blocks (bijective).
    const int lin = blockIdx.x;
    const int s   = (lin & 7) * (NBLK / 8) + (lin >> 3);
    const int bx  = s % GXT;
    const int r1  = s / GXT;
    const int by  = r1 % GYT;
    const int r2  = r1 / GYT;
    const int zc  = r2 % GZT;
    const int b   = r2 / GZT;

    const int x0 = bx * TX;
    const int y0 = by * TY;
    const int z0 = zc * ZC;

    __shared__ __align__(16) __half Zq[5 * ZQQ];   // 9680 B; Sq aliases low words
    __shared__ __align__(16) __half Rq[5 * RQQ];   // 9680 B
    __shared__ float redbuf[4];
    __half* const Sq = Zq;   // alias: Zq fully consumed in P2 (barrier-separated)

    // ---- float4 column ownership: 240 tasks = 24 rows x 10 groups ----
    const bool is_col = (tid < 240);
    const int  crow = tid / 10;          // 0..23
    const int  cxg  = tid - crow * 10;   // 0..9
    const int  gy = y0 - 4 + crow;
    const int  gx = x0 - 4 + cxg * 4;    // 4-aligned; fully valid or fully OOB
    const bool vxy = is_col && ((unsigned)gy < (unsigned)NY) && (gx >= 0) && (gx <= NX - 4);
    const size_t cbase = (size_t)b * VOL + (vxy ? (size_t)(gy * NX + gx) : 0);
    const float* const baseI = I_targ + cbase;
    const float* const baseJ = J_pred + cbase;

    // ---- running z-box-sums over 4 owned columns (fp32, exact sliding) ----
    const float4 f40 = make_float4(0.f, 0.f, 0.f, 0.f);
    float4 rS0 = f40, rS1 = f40, rS2 = f40, rS3 = f40, rS4 = f40;

    // warmup: add slices z0-5 .. z0+3 (9 slices; OOB z -> zeros). Main loop
    // always subtracts z0+so-5; at so=0 that removes the z0-5 slice added
    // here (cancellation exact: absmax 0.0 in v2-v11 with this scheme).
#pragma unroll 3
    for (int ss = 0; ss < 9; ++ss) {
        const int z = z0 - 5 + ss;
        float4 aI = f40, aJ = f40;
        if (vxy && (unsigned)z < (unsigned)NZ) {
            aI = *(const float4*)(baseI + (size_t)z * SLICE);
            aJ = *(const float4*)(baseJ + (size_t)z * SLICE);
        }
        rS0 = f4add(rS0, aI);
        rS1 = f4add(rS1, aJ);
        rS2 = f4add(rS2, f4mul(aI, aI));
        rS3 = f4add(rS3, f4mul(aJ, aJ));
        rS4 = f4add(rS4, f4mul(aI, aJ));
    }

    // pending (prefetched) slices for so = 0
    float4 nIa = f40, nJa = f40, nIs = f40, nJs = f40;
    if (vxy) {
        const int za = z0 + 4;                 // always < NZ
        nIa = *(const float4*)(baseI + (size_t)za * SLICE);
        nJa = *(const float4*)(baseJ + (size_t)za * SLICE);
        const int zs = z0 - 5;
        if (zs >= 0) {
            nIs = *(const float4*)(baseI + (size_t)zs * SLICE);
            nJs = *(const float4*)(baseJ + (size_t)zs * SLICE);
        }
    }

    const int ty  = tid >> 4;      // 0..15
    const int tx2 = tid & 15;      // x-pair index (2 voxels/thread)
    float acc = 0.f;

#pragma unroll 1
    for (int so = 0; so < ZC; ++so) {
        // P0: consume pending add/sub slices, slide z-window (fp32)
        rS0 = f4add(rS0, f4sub(nIa, nIs));
        rS1 = f4add(rS1, f4sub(nJa, nJs));
        rS2 = f4add(rS2, f4sub(f4mul(nIa, nIa), f4mul(nIs, nIs)));
        rS3 = f4add(rS3, f4sub(f4mul(nJa, nJa), f4mul(nJs, nJs)));
        rS4 = f4add(rS4, f4sub(f4mul(nIa, nJa), f4mul(nIs, nJs)));

        // issue next step's loads NOW — they stay in flight across all four
        // lgkm-only barriers and are consumed at the next P0.
        nIa = f40; nJa = f40; nIs = f40; nJs = f40;
        if (so < ZC - 1 && vxy) {
            const int za = z0 + 5 + so;
            if (za < NZ) {
                nIa = *(const float4*)(baseI + (size_t)za * SLICE);
                nJa = *(const float4*)(baseJ + (size_t)za * SLICE);
            }
            const int zs = z0 + so - 4;
            if (zs >= 0) {   // zs <= z0+ZC-2 < NZ always
                nIs = *(const float4*)(baseI + (size_t)zs * SLICE);
                nJs = *(const float4*)(baseJ + (size_t)zs * SLICE);
            }
        }

        // P1: stage z-sums as fp16 (b64 per quantity; zeros for invalid cols)
        if (is_col) {
            const int o = crow * ZRS + cxg * 4;
            union { uint2 u; __half2 h[2]; } pk;
            pk.h[0] = __float22half2_rn(make_float2(rS0.x, rS0.y));
            pk.h[1] = __float22half2_rn(make_float2(rS0.z, rS0.w));
            *(uint2*)&Zq[0 * ZQQ + o] = pk.u;
            pk.h[0] = __float22half2_rn(make_float2(rS1.x, rS1.y));
            pk.h[1] = __float22half2_rn(make_float2(rS1.z, rS1.w));
            *(uint2*)&Zq[1 * ZQQ + o] = pk.u;
            pk.h[0] = __float22half2_rn(make_float2(rS2.x, rS2.y));
            pk.h[1] = __float22half2_rn(make_float2(rS2.z, rS2.w));
            *(uint2*)&Zq[2 * ZQQ + o] = pk.u;
            pk.h[0] = __float22half2_rn(make_float2(rS3.x, rS3.y));
            pk.h[1] = __float22half2_rn(make_float2(rS3.z, rS3.w));
            *(uint2*)&Zq[3 * ZQQ + o] = pk.u;
            pk.h[0] = __float22half2_rn(make_float2(rS4.x, rS4.y));
            pk.h[1] = __float22half2_rn(make_float2(rS4.z, rS4.w));
            *(uint2*)&Zq[4 * ZQQ + o] = pk.u;
        }
        lds_barrier();

        // P2: x-boxsum, 240 half-row tasks = 24 rows x 5 q x 2 halves.
        // Read 24 fp16 (3 b128), slide 16 outputs in fp32, write 2 b128.
        if (tid < 240) {
            const int q   = tid / 48;
            const int rem = tid - q * 48;
            const int row = rem >> 1;
            const int h   = rem & 1;
            const __half* src = &Zq[q * ZQQ + row * ZRS + h * 16];
            float c[24];
#pragma unroll
            for (int g = 0; g < 3; ++g) {
                U8 v = ld8(src + g * 8);
#pragma unroll
                for (int j = 0; j < 4; ++j) {
                    const float2 f = __half22float2(v.h[j]);
                    c[g * 8 + j * 2 + 0] = f.x;
                    c[g * 8 + j * 2 + 1] = f.y;
                }
            }
            float sx = c[0] + c[1] + c[2] + c[3] + c[4]
                     + c[5] + c[6] + c[7] + c[8];
            float o[16];
            o[0] = sx;
#pragma unroll
            for (int i = 1; i < 16; ++i) { sx += c[i + 8] - c[i - 1]; o[i] = sx; }
            __half* dst = &Rq[q * RQQ + row * RRS + h * 16];
#pragma unroll
            for (int g = 0; g < 2; ++g) {
                U8 w;
#pragma unroll
                for (int j = 0; j < 4; ++j)
                    w.h[j] = __float22half2_rn(make_float2(o[g * 8 + j * 2],
                                                           o[g * 8 + j * 2 + 1]));
                st8(dst + g * 8, w);
            }
        }
        lds_barrier();

        // P3: y-boxsum, 80 tasks = 5 q x 4 x-groups(8 wide) x 4 row-quarters.
        // Packed fp16 slide (no cvt): 12 b128 reads, 4 b128 writes.
        if (tid < 80) {
            const int q  = tid / 16;
            const int rm = tid & 15;
            const int xg = rm >> 2;    // 0..3 (8 x's each)
            const int q4 = rm & 3;     // row quarter (4 output rows)
            const __half* rb = &Rq[q * RQQ + (q4 * 4) * RRS + xg * 8];
            __half* sb = &Sq[q * SQQ + (q4 * 4) * SRS + xg * 8];
            U8 sum = ld8(rb);
#pragma unroll
            for (int k = 1; k < 9; ++k) {
                const U8 t = ld8(rb + k * RRS);
#pragma unroll
                for (int j = 0; j < 4; ++j) sum.h[j] = __hadd2(sum.h[j], t.h[j]);
            }
            st8(sb, sum);
#pragma unroll
            for (int i = 1; i < 4; ++i) {
                const U8 nw = ld8(rb + (i + 8) * RRS);
                const U8 od = ld8(rb + (i - 1) * RRS);
#pragma unroll
                for (int j = 0; j < 4; ++j)
                    sum.h[j] = __hadd2(sum.h[j], __hsub2(nw.h[j], od.h[j]));
                st8(sb + i * SRS, sum);
            }
        }
        lds_barrier();

        // P4: cc for 2 voxels per thread (packed half2 reads, fp32 math)
        {
            const int o = ty * SRS + tx2 * 2;
            const float2 S0 = __half22float2(*(const __half2*)&Sq[0 * SQQ + o]);
            const float2 S1 = __half22float2(*(const __half2*)&Sq[1 * SQQ + o]);
            const float2 S2 = __half22float2(*(const __half2*)&Sq[2 * SQQ + o]);
            const float2 S3 = __half22float2(*(const __half2*)&Sq[3 * SQQ + o]);
            const float2 S4 = __half22float2(*(const __half2*)&Sq[4 * SQQ + o]);
            {
                const float cross = S4.x - S0.x * S1.x * INV729;
                const float Iv    = S2.x - S0.x * S0.x * INV729;
                const float Jv    = S3.x - S1.x * S1.x * INV729;
                acc += (cross * cross) / (Iv * Jv + 1e-5f);
            }
            {
                const float cross = S4.y - S0.y * S1.y * INV729;
                const float Iv    = S2.y - S0.y * S0.y * INV729;
                const float Jv    = S3.y - S1.y * S1.y * INV729;
                acc += (cross * cross) / (Iv * Jv + 1e-5f);
            }
        }
        lds_barrier();   // Sq(=Zq) reads must precede next step's P1 Zq writes
    }

    // ---- block reduction (deterministic within block) ----
#pragma unroll
    for (int off = 32; off > 0; off >>= 1) acc += __shfl_down(acc, off);
    __syncthreads();
    if ((tid & 63) == 0) redbuf[tid >> 6] = acc;
    __syncthreads();
    if (tid == 0) partial[s] = redbuf[0] + redbuf[1] + redbuf[2] + redbuf[3];
}

__global__ __launch_bounds__(256) void ncc_final(
    const float* __restrict__ partial, float* __restrict__ out)
{
    __shared__ float sm[256];
    const int tid = threadIdx.x;
    float v = 0.f;
    for (int i = tid; i < NBLK; i += 256) v += partial[i];
    sm[tid] = v;
    __syncthreads();
#pragma unroll
    for (int w = 128; w > 0; w >>= 1) {
        if (tid < w) sm[tid] += sm[tid + w];
        __syncthreads();
    }
    if (tid == 0) out[0] = 1.0f - sm[0] * (1.0f / (float)TOTAL);
}

extern "C" void kernel_launch(void* const* d_in, const int* in_sizes, int n_in,
                              void* d_out, int out_size, void* d_ws, size_t ws_size,
                              hipStream_t stream)
{
    const float* predict = (const float*)d_in[0];  // J
    const float* target  = (const float*)d_in[1];  // I
    float* partial = (float*)d_ws;                 // 3840 floats (15.4 KB)

    ncc_main<<<dim3(NBLK), 256, 0, stream>>>(predict, target, partial);
    ncc_final<<<1, 256, 0, stream>>>(partial, (float*)d_out);
}